// Round 11
// baseline (606.085 us; speedup 1.0000x reference)
//
#include <hip/hip_runtime.h>

typedef _Float16 half8 __attribute__((ext_vector_type(8)));
typedef float f32x4 __attribute__((ext_vector_type(4)));

#define DIM 256
#define NE 1024
#define NROWS 131072
#define DECAY 0.99f
#define ONE_MINUS 0.01f
#define EPS 1e-5f

// output offsets (floats) in d_out, concatenated in reference return order
#define OFF_Q    0u
#define OFF_DIFF 33554432u
#define OFF_IND  33554433u
#define OFF_NEMB 33685505u
#define OFF_NCS  33947649u
#define OFF_NEA  33948673u

#define MFMA16(a, b, c) __builtin_amdgcn_mfma_f32_16x16x32_f16(a, b, c, 0, 0, 0)

// ---------------- K0: codebook transpose (LDS-tiled, coalesced both sides) ----
__global__ void k0_prep(const float* __restrict__ embed,
                        _Float16* __restrict__ bt_hi,
                        float* __restrict__ embT) {
    __shared__ float T[64][65];
    int t = threadIdx.x;
    int j0 = blockIdx.x * 64, d0 = blockIdx.y * 64;
    #pragma unroll
    for (int p = 0; p < 16; ++p) {
        int dd = p * 4 + (t >> 6), jj = t & 63;
        T[jj][dd] = embed[(size_t)(d0 + dd) * NE + j0 + jj];
    }
    __syncthreads();
    #pragma unroll
    for (int p = 0; p < 16; ++p) {
        int jj = p * 4 + (t >> 6), dd = t & 63;
        float e = T[jj][dd];
        int j = j0 + jj, d = d0 + dd;
        embT[(size_t)j * DIM + d] = e;
        bt_hi[(size_t)j * DIM + d] = (_Float16)e;
    }
}

// ---------------- K0b: sqh[j] = 0.5*||e_j||^2 (exact f32) ----------------
__global__ void k0b_sq(const float* __restrict__ embT, float* __restrict__ sqh) {
    int w = threadIdx.x >> 6, l = threadIdx.x & 63;
    int j = blockIdx.x * 4 + w;
    f32x4 v = *(const f32x4*)(embT + (size_t)j * DIM + l * 4);
    float s = v[0] * v[0] + v[1] * v[1] + v[2] * v[2] + v[3] * v[3];
    for (int off = 32; off; off >>= 1) s += __shfl_down(s, off);
    if (l == 0) sqh[j] = 0.5f * s;
}

// ---------------- K0c: input f32 -> f16 plane (scratch in out-Q region) --------
__global__ void k0c_cvt(const float* __restrict__ input, _Float16* __restrict__ qhi) {
    size_t i = ((size_t)blockIdx.x * 256 + threadIdx.x) * 8;
    f32x4 a = *(const f32x4*)(input + i);
    f32x4 b = *(const f32x4*)(input + i + 4);
    half8 h;
    h[0] = (_Float16)a[0]; h[1] = (_Float16)a[1];
    h[2] = (_Float16)a[2]; h[3] = (_Float16)a[3];
    h[4] = (_Float16)b[0]; h[5] = (_Float16)b[1];
    h[6] = (_Float16)b[2]; h[7] = (_Float16)b[3];
    *(half8*)(qhi + i) = h;
}

// ---------------- K1: code-resident streaming distance GEMM ----------------
// Wave pins 32 codes as MFMA A-operand (64 VGPR, loaded once); streams input
// row-tiles as B-operand from the f16 plane. D: col=lane&15 = input row,
// regs = codes -> argmin over codes is lane-local + 2 shfl levels. Winner
// merged globally via atomicMin on an order-preserving (val,idx) u64 key.
// No LDS, no barriers, no per-row resident state -> no spill pressure.
__global__ __launch_bounds__(256)
void k1_stream(const _Float16* __restrict__ qhi,
               const _Float16* __restrict__ bt_hi,
               const float* __restrict__ sqh,
               unsigned long long* __restrict__ keys) {
    const int b = blockIdx.x;
    const int q = (b >> 3) & 7;                 // code-block 0..7 (128 codes)
    const int r = (b & 7) + ((b >> 6) << 3);    // rowchunk 0..1023 (XCD-colocated)
    const int w = threadIdx.x >> 6, l = threadIdx.x & 63;
    const int lr = l & 15, lg = l >> 4;
    const int cq = q * 128 + w * 32;            // wave's 32 codes

    // codes -> registers (A-operand fragments), once
    half8 A0[8], A1[8];
    {
        const _Float16* bp0 = bt_hi + (size_t)(cq + lr) * DIM + lg * 8;
        #pragma unroll
        for (int kf = 0; kf < 8; ++kf) {
            A0[kf] = *(const half8*)(bp0 + kf * 32);
            A1[kf] = *(const half8*)(bp0 + 16 * DIM + kf * 32);
        }
    }
    // sq for the lane's 8 codes (D-rows lg*4+e, tiles 0/1)
    float sq0[4], sq1[4];
    #pragma unroll
    for (int e = 0; e < 4; ++e) {
        sq0[e] = sqh[cq + lg * 4 + e];
        sq1[e] = sqh[cq + 16 + lg * 4 + e];
    }

    const int rowb = r * 128;
    #pragma unroll 1
    for (int m = 0; m < 8; ++m) {
        const _Float16* xp = qhi + (size_t)(rowb + m * 16 + lr) * DIM + lg * 8;
        f32x4 acc0 = {0.f, 0.f, 0.f, 0.f}, acc1 = {0.f, 0.f, 0.f, 0.f};
        #pragma unroll
        for (int kf = 0; kf < 8; ++kf) {
            half8 x = *(const half8*)(xp + kf * 32);
            acc0 = MFMA16(A0[kf], x, acc0);
            acc1 = MFMA16(A1[kf], x, acc1);
        }
        // lane-local best over 8 codes (ascending idx -> lowest-index tie-break)
        float bv = sq0[0] - acc0[0];
        int   bi = cq + lg * 4;
        #pragma unroll
        for (int e = 1; e < 4; ++e) {
            float v = sq0[e] - acc0[e];
            if (v < bv) { bv = v; bi = cq + lg * 4 + e; }
        }
        #pragma unroll
        for (int e = 0; e < 4; ++e) {
            float v = sq1[e] - acc1[e];
            if (v < bv) { bv = v; bi = cq + 16 + lg * 4 + e; }
        }
        // order-preserving pack: (sortable-float << 32) | idx
        unsigned uv = __float_as_uint(bv);
        uv = (uv >> 31) ? ~uv : (uv | 0x80000000u);
        unsigned long long key = ((unsigned long long)uv << 32) | (unsigned)bi;
        // reduce across the 4 lane-groups sharing this input row
        unsigned long long ok = __shfl_xor(key, 16);
        if (ok < key) key = ok;
        ok = __shfl_xor(key, 32);
        if (ok < key) key = ok;
        if (l < 16) atomicMin(&keys[rowb + m * 16 + lr], key);
    }
}

// ---------------- K1b: key -> index/hist + quantize + exact diff ----------------
__global__ __launch_bounds__(256)
void k1b_final(const unsigned long long* __restrict__ keys,
               const float* __restrict__ input,
               const float* __restrict__ embT,
               float* __restrict__ out,
               int* __restrict__ jint,
               int* __restrict__ counts,
               float* __restrict__ diffpart) {
    __shared__ int jm_lds[64];
    __shared__ float dred[4];
    int t = threadIdx.x;
    int rb = blockIdx.x * 64;
    if (t < 64) {
        int row = rb + t;
        int jm = (int)(unsigned)(keys[row] & 0xFFFFFFFFull);
        out[OFF_IND + row] = (float)jm;
        jint[row] = jm;
        atomicAdd(&counts[jm], 1);
        jm_lds[t] = jm;
    }
    __syncthreads();
    int rr = t >> 2, ds = (t & 3) * 64;
    int row = rb + rr;
    int jm = jm_lds[rr];
    const float* qp = embT + (size_t)jm * DIM + ds;
    const float* xp = input + (size_t)row * DIM + ds;
    float* op = out + OFF_Q + (size_t)row * DIM + ds;
    float dsum = 0.f;
    #pragma unroll
    for (int i = 0; i < 16; ++i) {
        f32x4 qv = *(const f32x4*)(qp + i * 4);
        f32x4 xv = *(const f32x4*)(xp + i * 4);
        *(f32x4*)(op + i * 4) = qv;
        f32x4 d = qv - xv;
        dsum += d[0] * d[0] + d[1] * d[1] + d[2] * d[2] + d[3] * d[3];
    }
    for (int off = 32; off; off >>= 1) dsum += __shfl_down(dsum, off);
    int w = t >> 6, l = t & 63;
    if (l == 0) dred[w] = dsum;
    __syncthreads();
    if (t == 0) diffpart[blockIdx.x] = dred[0] + dred[1] + dred[2] + dred[3];
}

// ---------------- K2: shfl-scan + EMA scalars + diff finalize (1 block, 1024 thr) ----
__global__ void k2_small(const float* __restrict__ cluster_size,
                         const int* __restrict__ counts,
                         const float* __restrict__ diffpart,
                         float* __restrict__ out,
                         int* __restrict__ offsets,
                         float* __restrict__ cs_ws) {
    __shared__ int   wtot[16];
    __shared__ float wsum[16], wdiff[16];
    int t = threadIdx.x, w = t >> 6, l = t & 63;
    int cnt = counts[t];
    float ncs = cluster_size[t] * DECAY + ONE_MINUS * (float)cnt;
    out[OFF_NCS + t] = ncs;

    int sc = cnt;
    #pragma unroll
    for (int off = 1; off < 64; off <<= 1) {
        int v = __shfl_up(sc, off);
        if (l >= off) sc += v;
    }
    float ws = ncs;
    float dp = diffpart[t] + diffpart[t + 1024];   // k1b grid = 2048 blocks
    #pragma unroll
    for (int off = 32; off; off >>= 1) {
        ws += __shfl_xor(ws, off);
        dp += __shfl_xor(dp, off);
    }
    if (l == 63) wtot[w] = sc;
    if (l == 0) { wsum[w] = ws; wdiff[w] = dp; }
    __syncthreads();
    int woff = 0; float n = 0.f, dtot = 0.f;
    #pragma unroll
    for (int i = 0; i < 16; ++i) {
        woff += (i < w) ? wtot[i] : 0;
        n += wsum[i];
        dtot += wdiff[i];
    }
    offsets[t] = woff + sc - cnt;       // exclusive prefix
    cs_ws[t] = (ncs + EPS) / (n + (float)NE * EPS) * n;
    if (t == 0) out[OFF_DIFF] = dtot / 33554432.0f;
}

// ---------------- K3: scatter row ids into per-code buckets ----------------
__global__ void k3_scatter(const int* __restrict__ jint,
                           const int* __restrict__ offsets,
                           int* __restrict__ cursors,
                           int* __restrict__ list) {
    int r = blockIdx.x * 256 + threadIdx.x;
    int j = jint[r];
    int pos = atomicAdd(&cursors[j], 1);
    list[offsets[j] + pos] = r;
}

// ---------------- K4: BALANCED segment sum over sorted list ----------------
#define K4FLUSH() do {                                                   \
    float* dst = embed_sum + (size_t)curj * DIM + l * 4;                 \
    atomicAdd(dst + 0, acc[0]); atomicAdd(dst + 1, acc[1]);              \
    atomicAdd(dst + 2, acc[2]); atomicAdd(dst + 3, acc[3]);              \
    acc[0] = acc[1] = acc[2] = acc[3] = 0.f;                             \
} while (0)

__global__ void k4_segsum(const float* __restrict__ input,
                          const int* __restrict__ jint,
                          const int* __restrict__ list,
                          float* __restrict__ embed_sum) {
    int wid = (blockIdx.x * 256 + threadIdx.x) >> 6;   // 0..4095
    int l = threadIdx.x & 63;
    int p0 = wid * 32;
    int row_l = list[p0 + (l & 31)];
    int j_l = jint[row_l];
    f32x4 acc = {0.f, 0.f, 0.f, 0.f};
    int curj = __shfl(j_l, 0);
    #pragma unroll 1
    for (int g = 0; g < 8; ++g) {
        int r0 = __shfl(row_l, 4 * g + 0), j0 = __shfl(j_l, 4 * g + 0);
        int r1 = __shfl(row_l, 4 * g + 1), j1 = __shfl(j_l, 4 * g + 1);
        int r2 = __shfl(row_l, 4 * g + 2), j2 = __shfl(j_l, 4 * g + 2);
        int r3 = __shfl(row_l, 4 * g + 3), j3 = __shfl(j_l, 4 * g + 3);
        f32x4 v0 = *(const f32x4*)(input + (size_t)r0 * DIM + l * 4);
        f32x4 v1 = *(const f32x4*)(input + (size_t)r1 * DIM + l * 4);
        f32x4 v2 = *(const f32x4*)(input + (size_t)r2 * DIM + l * 4);
        f32x4 v3 = *(const f32x4*)(input + (size_t)r3 * DIM + l * 4);
        if (j0 != curj) { K4FLUSH(); curj = j0; }
        acc += v0;
        if (j1 != curj) { K4FLUSH(); curj = j1; }
        acc += v1;
        if (j2 != curj) { K4FLUSH(); curj = j2; }
        acc += v2;
        if (j3 != curj) { K4FLUSH(); curj = j3; }
        acc += v3;
    }
    K4FLUSH();
}

// ---------------- K5: transpose + EMA outputs (LDS-tiled, coalesced) ----------
__global__ void k5_ema(const float* __restrict__ embed_sum,
                       const float* __restrict__ embed_avg,
                       const float* __restrict__ cs_ws,
                       float* __restrict__ out) {
    __shared__ float T[64][65];
    int t = threadIdx.x;
    int j0 = blockIdx.x * 64, d0 = blockIdx.y * 64;
    #pragma unroll
    for (int p = 0; p < 16; ++p) {
        int jj = p * 4 + (t >> 6), dd = t & 63;
        T[dd][jj] = embed_sum[(size_t)(j0 + jj) * DIM + d0 + dd];
    }
    __syncthreads();
    #pragma unroll
    for (int p = 0; p < 16; ++p) {
        int dd = p * 4 + (t >> 6), jj = t & 63;
        int d = d0 + dd, j = j0 + jj;
        float sum = T[dd][jj];
        float na = embed_avg[(size_t)d * NE + j] * DECAY + ONE_MINUS * sum;
        out[OFF_NEA + (size_t)d * NE + j] = na;
        out[OFF_NEMB + (size_t)d * NE + j] = na / cs_ws[j];
    }
}

extern "C" void kernel_launch(void* const* d_in, const int* in_sizes, int n_in,
                              void* d_out, int out_size, void* d_ws, size_t ws_size,
                              hipStream_t stream) {
    const float* input        = (const float*)d_in[0];
    const float* embed        = (const float*)d_in[1];
    const float* cluster_size = (const float*)d_in[2];
    const float* embed_avg    = (const float*)d_in[3];
    float* out = (float*)d_out;
    char* ws = (char*)d_ws;

    _Float16* bt_hi  = (_Float16*)(ws + 0);             // 512 KB
    float*    embT   = (float*)(ws + 1048576);          // 1 MB
    float*    sqh    = (float*)(ws + 2097152);          // 4 KB
    int*      counts = (int*)(ws + 2101248);
    int*      offsets= (int*)(ws + 2105344);
    int*      cursors= (int*)(ws + 2113536);
    int*      jint   = (int*)(ws + 2117632);            // 512 KB
    int*      list   = (int*)(ws + 2641920);            // 512 KB
    float*    diffpart = (float*)(ws + 3166208);        // 2048 floats
    float*    cs_ws  = (float*)(ws + 3174400);
    unsigned long long* keys = (unsigned long long*)(ws + 3178496);  // 1 MB
    // embed_sum overlays the dead bt_hi region after k1_stream
    float*    embed_sum = (float*)(ws + 0);             // [1024][256] f32
    // f16 input plane scratch: lives in out's Q region until k1b overwrites it
    _Float16* qhi = (_Float16*)(out + OFF_Q);           // 67 MB

    hipMemsetAsync(counts, 0, 4096, stream);
    hipMemsetAsync(cursors, 0, 4096, stream);
    hipMemsetAsync(keys, 0xFF, (size_t)NROWS * 8, stream);

    k0_prep<<<dim3(16, 4), 256, 0, stream>>>(embed, bt_hi, embT);
    k0b_sq<<<256, 256, 0, stream>>>(embT, sqh);
    k0c_cvt<<<16384, 256, 0, stream>>>(input, qhi);
    k1_stream<<<8192, 256, 0, stream>>>(qhi, bt_hi, sqh, keys);
    k1b_final<<<2048, 256, 0, stream>>>(keys, input, embT, out, jint, counts, diffpart);
    // bt_hi dead after k1_stream -> zero that region for embed_sum accumulation
    hipMemsetAsync(embed_sum, 0, (size_t)NE * DIM * sizeof(float), stream);
    k2_small<<<1, 1024, 0, stream>>>(cluster_size, counts, diffpart, out, offsets, cs_ws);
    k3_scatter<<<512, 256, 0, stream>>>(jint, offsets, cursors, list);
    k4_segsum<<<1024, 256, 0, stream>>>(input, jint, list, embed_sum);
    k5_ema<<<dim3(16, 4), 256, 0, stream>>>(embed_sum, embed_avg, cs_ws, out);
}

// Round 12
// 502.495 us; speedup vs baseline: 1.2061x; 1.2061x over previous
//
#include <hip/hip_runtime.h>

typedef _Float16 half8 __attribute__((ext_vector_type(8)));
typedef float f32x4 __attribute__((ext_vector_type(4)));

#define DIM 256
#define NE 1024
#define NROWS 131072
#define DECAY 0.99f
#define ONE_MINUS 0.01f
#define EPS 1e-5f

// output offsets (floats) in d_out, concatenated in reference return order
#define OFF_Q    0u
#define OFF_DIFF 33554432u
#define OFF_IND  33554433u
#define OFF_NEMB 33685505u
#define OFF_NCS  33947649u
#define OFF_NEA  33948673u

#define MFMA16(a, b, c) __builtin_amdgcn_mfma_f32_16x16x32_f16(a, b, c, 0, 0, 0)

// ---------------- K0: codebook transpose (LDS-tiled, coalesced both sides) ----
__global__ void k0_prep(const float* __restrict__ embed,
                        _Float16* __restrict__ bt_hi,
                        float* __restrict__ embT) {
    __shared__ float T[64][65];
    int t = threadIdx.x;
    int j0 = blockIdx.x * 64, d0 = blockIdx.y * 64;
    #pragma unroll
    for (int p = 0; p < 16; ++p) {
        int dd = p * 4 + (t >> 6), jj = t & 63;
        T[jj][dd] = embed[(size_t)(d0 + dd) * NE + j0 + jj];
    }
    __syncthreads();
    #pragma unroll
    for (int p = 0; p < 16; ++p) {
        int jj = p * 4 + (t >> 6), dd = t & 63;
        float e = T[jj][dd];
        int j = j0 + jj, d = d0 + dd;
        embT[(size_t)j * DIM + d] = e;
        bt_hi[(size_t)j * DIM + d] = (_Float16)e;
    }
}

// ---------------- K0b: sqh[j] = 0.5*||e_j||^2 (exact f32) ----------------
__global__ void k0b_sq(const float* __restrict__ embT, float* __restrict__ sqh) {
    int w = threadIdx.x >> 6, l = threadIdx.x & 63;
    int j = blockIdx.x * 4 + w;
    f32x4 v = *(const f32x4*)(embT + (size_t)j * DIM + l * 4);
    float s = v[0] * v[0] + v[1] * v[1] + v[2] * v[2] + v[3] * v[3];
    for (int off = 32; off; off >>= 1) s += __shfl_down(s, off);
    if (l == 0) sqh[j] = 0.5f * s;
}

// ---------------- K0c: input f32 -> f16, FRAGMENT-MAJOR layout ----------------
// For 16-row tile T, fragment (kf, lane(lr,lg)) stored contiguously so a wave's
// B-fragment load is one 1KB coalesced burst:
//   qhiT[ (T*8 + kf)*512 + lr*32 + lg*8 + i ]  <-  input[T*16+lr][kf*32+lg*8+i]
__global__ void k0c_cvt(const float* __restrict__ input, _Float16* __restrict__ qhiT) {
    size_t i8 = (size_t)blockIdx.x * 256 + threadIdx.x;   // one 8-float chunk
    size_t row = i8 >> 5;
    int c = (int)(i8 & 31);          // chunk-in-row: kf = c>>2, lg = c&3
    const float* src = input + i8 * 8;
    f32x4 a = *(const f32x4*)(src);
    f32x4 b = *(const f32x4*)(src + 4);
    half8 h;
    h[0] = (_Float16)a[0]; h[1] = (_Float16)a[1];
    h[2] = (_Float16)a[2]; h[3] = (_Float16)a[3];
    h[4] = (_Float16)b[0]; h[5] = (_Float16)b[1];
    h[6] = (_Float16)b[2]; h[7] = (_Float16)b[3];
    size_t dst = ((row >> 4) * 8 + (c >> 2)) * 512 + (row & 15) * 32 + (c & 3) * 8;
    *(half8*)(qhiT + dst) = h;
}

// ---------------- K1: code-resident streaming distance GEMM ----------------
// Wave pins 32 codes as A-operand (64 VGPR); streams input row-tiles (frag-major,
// 1KB coalesced loads) as B. Per-row winner over the wave's 32 codes stored as a
// PLAIN u64 key to part[qw][row] (no atomics in the hot loop -- R11's clog).
__global__ __launch_bounds__(256)
void k1_stream(const _Float16* __restrict__ qhiT,
               const _Float16* __restrict__ bt_hi,
               const float* __restrict__ sqh,
               unsigned long long* __restrict__ part) {
    const int b = blockIdx.x;
    const int q = (b >> 3) & 7;                 // code-block 0..7 (128 codes)
    const int r = (b & 7) + ((b >> 6) << 3);    // rowchunk 0..1023 (XCD-colocated)
    const int w = threadIdx.x >> 6, l = threadIdx.x & 63;
    const int lr = l & 15, lg = l >> 4;
    const int cq = q * 128 + w * 32;            // wave's 32 codes

    // codes -> registers (A-operand fragments), once
    half8 A0[8], A1[8];
    {
        const _Float16* bp0 = bt_hi + (size_t)(cq + lr) * DIM + lg * 8;
        #pragma unroll
        for (int kf = 0; kf < 8; ++kf) {
            A0[kf] = *(const half8*)(bp0 + kf * 32);
            A1[kf] = *(const half8*)(bp0 + 16 * DIM + kf * 32);
        }
    }
    float sq0[4], sq1[4];
    #pragma unroll
    for (int e = 0; e < 4; ++e) {
        sq0[e] = sqh[cq + lg * 4 + e];
        sq1[e] = sqh[cq + 16 + lg * 4 + e];
    }

    const int rowb = r * 128;
    // fragment base for this lane: tile m, frag kf at + (m*8+kf)*512
    const _Float16* xb0 = qhiT + (size_t)r * 32768 + lr * 32 + lg * 8;
    unsigned long long* pout = part + (size_t)(q * 4 + w) * NROWS + rowb + lr;

    half8 xa[8], xn[8];
    #pragma unroll
    for (int kf = 0; kf < 8; ++kf) xa[kf] = *(const half8*)(xb0 + kf * 512);

    #pragma unroll
    for (int m = 0; m < 8; ++m) {
        // prefetch next tile's fragments (latency hides under MFMAs)
        if (m < 7) {
            const _Float16* xp = xb0 + (m + 1) * 4096;
            #pragma unroll
            for (int kf = 0; kf < 8; ++kf) xn[kf] = *(const half8*)(xp + kf * 512);
        }

        f32x4 aAe = {0.f,0.f,0.f,0.f}, aAo = {0.f,0.f,0.f,0.f};
        f32x4 aBe = {0.f,0.f,0.f,0.f}, aBo = {0.f,0.f,0.f,0.f};
        __builtin_amdgcn_s_setprio(1);
        #pragma unroll
        for (int kf = 0; kf < 8; kf += 2) {
            aAe = MFMA16(A0[kf],     xa[kf],     aAe);
            aBe = MFMA16(A1[kf],     xa[kf],     aBe);
            aAo = MFMA16(A0[kf + 1], xa[kf + 1], aAo);
            aBo = MFMA16(A1[kf + 1], xa[kf + 1], aBo);
        }
        __builtin_amdgcn_s_setprio(0);
        f32x4 d0 = aAe + aAo;   // codes cq + lg*4+e      (this lane's col = row lr)
        f32x4 d1 = aBe + aBo;   // codes cq + 16 + lg*4+e

        // lane-local best over 8 codes (ascending idx -> lowest-index tie-break)
        float bv = sq0[0] - d0[0];
        int   bi = cq + lg * 4;
        #pragma unroll
        for (int e = 1; e < 4; ++e) {
            float v = sq0[e] - d0[e];
            if (v < bv) { bv = v; bi = cq + lg * 4 + e; }
        }
        #pragma unroll
        for (int e = 0; e < 4; ++e) {
            float v = sq1[e] - d1[e];
            if (v < bv) { bv = v; bi = cq + 16 + lg * 4 + e; }
        }
        // order-preserving pack: (sortable-float << 32) | idx
        unsigned uv = __float_as_uint(bv);
        uv = (uv >> 31) ? ~uv : (uv | 0x80000000u);
        unsigned long long key = ((unsigned long long)uv << 32) | (unsigned)bi;
        // min across the 4 lane-groups sharing this row
        unsigned long long ok = __shfl_xor(key, 16);
        if (ok < key) key = ok;
        ok = __shfl_xor(key, 32);
        if (ok < key) key = ok;
        if (l < 16) pout[m * 16] = key;     // plain store, zero contention

        #pragma unroll
        for (int kf = 0; kf < 8; ++kf) xa[kf] = xn[kf];
    }
}

// ---------------- K1b_idx: reduce 32 partials/row -> index/hist ----------------
__global__ __launch_bounds__(256)
void k1b_idx(const unsigned long long* __restrict__ part,
             float* __restrict__ out,
             int* __restrict__ jint,
             int* __restrict__ counts) {
    int row = blockIdx.x * 256 + threadIdx.x;
    unsigned long long best = part[row];
    #pragma unroll
    for (int qw = 1; qw < 32; ++qw) {
        unsigned long long v = part[(size_t)qw * NROWS + row];
        if (v < best) best = v;
    }
    int jm = (int)(unsigned)(best & 0xFFFFFFFFull);
    out[OFF_IND + row] = (float)jm;
    jint[row] = jm;
    atomicAdd(&counts[jm], 1);
}

// ---------------- K1b_q: quantize gather/write + exact f32 diff ----------------
__global__ __launch_bounds__(256)
void k1b_q(const int* __restrict__ jint,
           const float* __restrict__ input,
           const float* __restrict__ embT,
           float* __restrict__ out,
           float* __restrict__ diffpart) {
    __shared__ int jm_lds[64];
    __shared__ float dred[4];
    int t = threadIdx.x;
    int rb = blockIdx.x * 64;
    if (t < 64) jm_lds[t] = jint[rb + t];
    __syncthreads();
    int rr = t >> 2, ds = (t & 3) * 64;
    int row = rb + rr;
    int jm = jm_lds[rr];
    const float* qp = embT + (size_t)jm * DIM + ds;
    const float* xp = input + (size_t)row * DIM + ds;
    float* op = out + OFF_Q + (size_t)row * DIM + ds;
    float dsum = 0.f;
    #pragma unroll
    for (int i = 0; i < 16; ++i) {
        f32x4 qv = *(const f32x4*)(qp + i * 4);
        f32x4 xv = *(const f32x4*)(xp + i * 4);
        *(f32x4*)(op + i * 4) = qv;
        f32x4 d = qv - xv;
        dsum += d[0] * d[0] + d[1] * d[1] + d[2] * d[2] + d[3] * d[3];
    }
    for (int off = 32; off; off >>= 1) dsum += __shfl_down(dsum, off);
    int w = t >> 6, l = t & 63;
    if (l == 0) dred[w] = dsum;
    __syncthreads();
    if (t == 0) diffpart[blockIdx.x] = dred[0] + dred[1] + dred[2] + dred[3];
}

// ---------------- K2: shfl-scan + EMA scalars + diff finalize (1 block, 1024 thr) ----
__global__ void k2_small(const float* __restrict__ cluster_size,
                         const int* __restrict__ counts,
                         const float* __restrict__ diffpart,
                         float* __restrict__ out,
                         int* __restrict__ offsets,
                         float* __restrict__ cs_ws) {
    __shared__ int   wtot[16];
    __shared__ float wsum[16], wdiff[16];
    int t = threadIdx.x, w = t >> 6, l = t & 63;
    int cnt = counts[t];
    float ncs = cluster_size[t] * DECAY + ONE_MINUS * (float)cnt;
    out[OFF_NCS + t] = ncs;

    int sc = cnt;
    #pragma unroll
    for (int off = 1; off < 64; off <<= 1) {
        int v = __shfl_up(sc, off);
        if (l >= off) sc += v;
    }
    float ws = ncs;
    float dp = diffpart[t] + diffpart[t + 1024];   // k1b_q grid = 2048 blocks
    #pragma unroll
    for (int off = 32; off; off >>= 1) {
        ws += __shfl_xor(ws, off);
        dp += __shfl_xor(dp, off);
    }
    if (l == 63) wtot[w] = sc;
    if (l == 0) { wsum[w] = ws; wdiff[w] = dp; }
    __syncthreads();
    int woff = 0; float n = 0.f, dtot = 0.f;
    #pragma unroll
    for (int i = 0; i < 16; ++i) {
        woff += (i < w) ? wtot[i] : 0;
        n += wsum[i];
        dtot += wdiff[i];
    }
    offsets[t] = woff + sc - cnt;       // exclusive prefix
    cs_ws[t] = (ncs + EPS) / (n + (float)NE * EPS) * n;
    if (t == 0) out[OFF_DIFF] = dtot / 33554432.0f;
}

// ---------------- K3: scatter row ids into per-code buckets ----------------
__global__ void k3_scatter(const int* __restrict__ jint,
                           const int* __restrict__ offsets,
                           int* __restrict__ cursors,
                           int* __restrict__ list) {
    int r = blockIdx.x * 256 + threadIdx.x;
    int j = jint[r];
    int pos = atomicAdd(&cursors[j], 1);
    list[offsets[j] + pos] = r;
}

// ---------------- K4: BALANCED segment sum over sorted list ----------------
#define K4FLUSH() do {                                                   \
    float* dst = embed_sum + (size_t)curj * DIM + l * 4;                 \
    atomicAdd(dst + 0, acc[0]); atomicAdd(dst + 1, acc[1]);              \
    atomicAdd(dst + 2, acc[2]); atomicAdd(dst + 3, acc[3]);              \
    acc[0] = acc[1] = acc[2] = acc[3] = 0.f;                             \
} while (0)

__global__ void k4_segsum(const float* __restrict__ input,
                          const int* __restrict__ jint,
                          const int* __restrict__ list,
                          float* __restrict__ embed_sum) {
    int wid = (blockIdx.x * 256 + threadIdx.x) >> 6;   // 0..4095
    int l = threadIdx.x & 63;
    int p0 = wid * 32;
    int row_l = list[p0 + (l & 31)];
    int j_l = jint[row_l];
    f32x4 acc = {0.f, 0.f, 0.f, 0.f};
    int curj = __shfl(j_l, 0);
    #pragma unroll 1
    for (int g = 0; g < 8; ++g) {
        int r0 = __shfl(row_l, 4 * g + 0), j0 = __shfl(j_l, 4 * g + 0);
        int r1 = __shfl(row_l, 4 * g + 1), j1 = __shfl(j_l, 4 * g + 1);
        int r2 = __shfl(row_l, 4 * g + 2), j2 = __shfl(j_l, 4 * g + 2);
        int r3 = __shfl(row_l, 4 * g + 3), j3 = __shfl(j_l, 4 * g + 3);
        f32x4 v0 = *(const f32x4*)(input + (size_t)r0 * DIM + l * 4);
        f32x4 v1 = *(const f32x4*)(input + (size_t)r1 * DIM + l * 4);
        f32x4 v2 = *(const f32x4*)(input + (size_t)r2 * DIM + l * 4);
        f32x4 v3 = *(const f32x4*)(input + (size_t)r3 * DIM + l * 4);
        if (j0 != curj) { K4FLUSH(); curj = j0; }
        acc += v0;
        if (j1 != curj) { K4FLUSH(); curj = j1; }
        acc += v1;
        if (j2 != curj) { K4FLUSH(); curj = j2; }
        acc += v2;
        if (j3 != curj) { K4FLUSH(); curj = j3; }
        acc += v3;
    }
    K4FLUSH();
}

// ---------------- K5: transpose + EMA outputs (LDS-tiled, coalesced) ----------
__global__ void k5_ema(const float* __restrict__ embed_sum,
                       const float* __restrict__ embed_avg,
                       const float* __restrict__ cs_ws,
                       float* __restrict__ out) {
    __shared__ float T[64][65];
    int t = threadIdx.x;
    int j0 = blockIdx.x * 64, d0 = blockIdx.y * 64;
    #pragma unroll
    for (int p = 0; p < 16; ++p) {
        int jj = p * 4 + (t >> 6), dd = t & 63;
        T[dd][jj] = embed_sum[(size_t)(j0 + jj) * DIM + d0 + dd];
    }
    __syncthreads();
    #pragma unroll
    for (int p = 0; p < 16; ++p) {
        int dd = p * 4 + (t >> 6), jj = t & 63;
        int d = d0 + dd, j = j0 + jj;
        float sum = T[dd][jj];
        float na = embed_avg[(size_t)d * NE + j] * DECAY + ONE_MINUS * sum;
        out[OFF_NEA + (size_t)d * NE + j] = na;
        out[OFF_NEMB + (size_t)d * NE + j] = na / cs_ws[j];
    }
}

extern "C" void kernel_launch(void* const* d_in, const int* in_sizes, int n_in,
                              void* d_out, int out_size, void* d_ws, size_t ws_size,
                              hipStream_t stream) {
    const float* input        = (const float*)d_in[0];
    const float* embed        = (const float*)d_in[1];
    const float* cluster_size = (const float*)d_in[2];
    const float* embed_avg    = (const float*)d_in[3];
    float* out = (float*)d_out;
    char* ws = (char*)d_ws;

    _Float16* bt_hi  = (_Float16*)(ws + 0);             // 512 KB
    float*    embT   = (float*)(ws + 1048576);          // 1 MB
    float*    sqh    = (float*)(ws + 2097152);          // 4 KB
    int*      counts = (int*)(ws + 2101248);
    int*      offsets= (int*)(ws + 2105344);
    int*      cursors= (int*)(ws + 2113536);
    int*      jint   = (int*)(ws + 2117632);            // 512 KB
    int*      list   = (int*)(ws + 2641920);            // 512 KB
    float*    diffpart = (float*)(ws + 3166208);        // 2048 floats
    float*    cs_ws  = (float*)(ws + 3174400);
    // embed_sum overlays the dead bt_hi region after k1_stream
    float*    embed_sum = (float*)(ws + 0);             // [1024][256] f32
    // scratch inside the out-Q region (consumed before k1b_q overwrites Q):
    //   qhiT: fragment-major f16 input plane, 64 MiB at Q[0..)
    //   part: 32 partial keys per row, 32 MiB at Q+64MiB
    _Float16* qhiT = (_Float16*)(out + OFF_Q);
    unsigned long long* part =
        (unsigned long long*)((char*)(out + OFF_Q) + (64u << 20));

    hipMemsetAsync(counts, 0, 4096, stream);
    hipMemsetAsync(cursors, 0, 4096, stream);

    k0_prep<<<dim3(16, 4), 256, 0, stream>>>(embed, bt_hi, embT);
    k0b_sq<<<256, 256, 0, stream>>>(embT, sqh);
    k0c_cvt<<<16384, 256, 0, stream>>>(input, qhiT);
    k1_stream<<<8192, 256, 0, stream>>>(qhiT, bt_hi, sqh, part);
    k1b_idx<<<512, 256, 0, stream>>>(part, out, jint, counts);
    k1b_q<<<2048, 256, 0, stream>>>(jint, input, embT, out, diffpart);
    // bt_hi dead after k1_stream -> zero that region for embed_sum accumulation
    hipMemsetAsync(embed_sum, 0, (size_t)NE * DIM * sizeof(float), stream);
    k2_small<<<1, 1024, 0, stream>>>(cluster_size, counts, diffpart, out, offsets, cs_ws);
    k3_scatter<<<512, 256, 0, stream>>>(jint, offsets, cursors, list);
    k4_segsum<<<1024, 256, 0, stream>>>(input, jint, list, embed_sum);
    k5_ema<<<dim3(16, 4), 256, 0, stream>>>(embed_sum, embed_avg, cs_ws, out);
}